// Round 13
// baseline (302.776 us; speedup 1.0000x reference)
//
#include <hip/hip_runtime.h>

// Problem constants
constexpr int T_ = 16;
constexpr int D_ = 192;
constexpr int H_ = 128;
constexpr int P_ = 128;
constexpr int EC_ = 32;
constexpr int S_ = T_ * D_;  // 3072
constexpr int FF_ = 512;
constexpr float SCALE_ = 0.17677669529663687f;  // 1/sqrt(32)

__device__ __forceinline__ float wave_sum64(float v) {
#pragma unroll
  for (int m = 1; m < 64; m <<= 1) v += __shfl_xor(v, m);
  return v;
}

// ---------------------------------------------------------------------------
// K1: embed + LN1 + qkv (layer 1), BM=6, NT=384, grid 512 (12 waves/CU).
// Also adjacency compaction on blocks < D_ (wave 0).
// ---------------------------------------------------------------------------
__global__ __launch_bounds__(384) void embed_qkv_kernel(
    const float* __restrict__ x, const float* __restrict__ W_node,
    const float* __restrict__ b_node, const float* __restrict__ time_enc,
    const float* __restrict__ edge_w, const float* __restrict__ Wqkv,
    const float* __restrict__ bqkv, const float* __restrict__ g1,
    const float* __restrict__ beta1, float* __restrict__ z,
    float* __restrict__ qkvb, int* __restrict__ adj_cnt,
    int* __restrict__ adj_list) {
  constexpr int BM = 6;
  int bx = blockIdx.x;
  int tid = threadIdx.x;
  if (bx < D_ && tid < 64) {  // adjacency row bx
    int lane = tid, cnt = 0;
    for (int base = 0; base < D_; base += 64) {
      int j = base + lane;
      bool pred = (edge_w[bx * D_ + j] > 0.f) || (j == bx);
      unsigned long long mb = __ballot(pred);
      int ofs = __popcll(mb & ((1ull << lane) - 1ull));
      if (pred) adj_list[bx * D_ + cnt + ofs] = j;
      cnt += __popcll(mb);
    }
    if (lane == 0) adj_cnt[bx] = cnt;
  }
  __shared__ float As[BM * 128];  // x-tile, later LN'd z
  __shared__ float zs[BM * 128];  // raw z
  int m0 = bx * BM;
  for (int idx = tid; idx < BM * 128; idx += 384) {
    int r = idx >> 7, h = idx & 127;
    int s = m0 + r, t = s / D_, d = s - t * D_;
    As[idx] = x[(t * H_ + h) * D_ + d];
  }
  __syncthreads();
  {  // embed: 3 rowgroups x 128 cols x 2 rows
    int rg = tid >> 7, col = tid & 127, r0 = rg * 2;
    float acc0 = b_node[col], acc1 = acc0;
    for (int h = 0; h < H_; h += 4) {
      float w0 = W_node[(h + 0) * P_ + col], w1 = W_node[(h + 1) * P_ + col];
      float w2 = W_node[(h + 2) * P_ + col], w3 = W_node[(h + 3) * P_ + col];
      const float4 a0 = *(const float4*)&As[r0 * 128 + h];
      const float4 a1 = *(const float4*)&As[(r0 + 1) * 128 + h];
      acc0 = fmaf(a0.x, w0, acc0); acc0 = fmaf(a0.y, w1, acc0);
      acc0 = fmaf(a0.z, w2, acc0); acc0 = fmaf(a0.w, w3, acc0);
      acc1 = fmaf(a1.x, w0, acc1); acc1 = fmaf(a1.y, w1, acc1);
      acc1 = fmaf(a1.z, w2, acc1); acc1 = fmaf(a1.w, w3, acc1);
    }
    float te = time_enc[col];
    int s0 = m0 + r0;
    float v0 = fmaxf(acc0, 0.f) + te * (float)(s0 / D_);
    float v1 = fmaxf(acc1, 0.f) + te * (float)((s0 + 1) / D_);
    zs[r0 * 128 + col] = v0;
    zs[(r0 + 1) * 128 + col] = v1;
    z[(size_t)s0 * P_ + col] = v0;
    z[(size_t)(s0 + 1) * P_ + col] = v1;
  }
  __syncthreads();
  {  // LN1: 6 waves, one row each -> As
    int wv = tid >> 6, lane = tid & 63;
    float v0 = zs[wv * 128 + lane], v1 = zs[wv * 128 + 64 + lane];
    float s = wave_sum64(v0 + v1);
    float mean = s * (1.f / 128.f);
    float d0 = v0 - mean, d1 = v1 - mean;
    float q = wave_sum64(d0 * d0 + d1 * d1);
    float inv = 1.f / sqrtf(q * (1.f / 128.f) + 1e-5f);
    As[wv * 128 + lane] = d0 * inv * g1[lane] + beta1[lane];
    As[wv * 128 + 64 + lane] = d1 * inv * g1[lane + 64] + beta1[lane + 64];
  }
  __syncthreads();
  {  // qkv: col = tid (384), 6 rows
    int col = tid;
    float acc[BM];
    float bc = bqkv[col];
#pragma unroll
    for (int r = 0; r < BM; ++r) acc[r] = bc;
    for (int k = 0; k < 128; k += 4) {
      float b0 = Wqkv[(size_t)(k + 0) * 384 + col];
      float b1 = Wqkv[(size_t)(k + 1) * 384 + col];
      float b2 = Wqkv[(size_t)(k + 2) * 384 + col];
      float b3 = Wqkv[(size_t)(k + 3) * 384 + col];
#pragma unroll
      for (int r = 0; r < BM; ++r) {
        const float4 a = *(const float4*)&As[r * 128 + k];
        acc[r] = fmaf(a.x, b0, acc[r]);
        acc[r] = fmaf(a.y, b1, acc[r]);
        acc[r] = fmaf(a.z, b2, acc[r]);
        acc[r] = fmaf(a.w, b3, acc[r]);
      }
    }
#pragma unroll
    for (int r = 0; r < BM; ++r) qkvb[(size_t)(m0 + r) * 384 + col] = acc[r];
  }
}

// ---------------------------------------------------------------------------
// Sparse attention + Wo projection + residual. One block (128 thr) per query.
// Key loops manually unrolled x2 for memory-level parallelism. (Proven R11.)
// ---------------------------------------------------------------------------
__global__ __launch_bounds__(128) void attn_wo_kernel(
    const float* __restrict__ qkvb, const int* __restrict__ adj_cnt,
    const int* __restrict__ adj_list, const float* __restrict__ Wo,
    const float* __restrict__ bo, float* __restrict__ z) {
  int s = blockIdx.x;
  int t = s / D_, d1 = s - t * D_;
  int tid = threadIdx.x;
  __shared__ int klist[D_];
  __shared__ float scores[4][2 * D_];
  __shared__ float att[128];

  int nd2 = adj_cnt[d1];
  for (int kd = tid; kd < nd2; kd += 128) klist[kd] = adj_list[d1 * D_ + kd];
  __syncthreads();
  int t0 = (t > 0) ? t - 1 : 0;
  int ntp = (t > 0) ? 2 : 1;
  int nk = nd2 * ntp;

  float q = qkvb[(size_t)s * 384 + tid];
  int h = tid >> 5, dd = tid & 31;

  for (int tp = 0; tp < ntp; ++tp) {
    int tt = t0 + tp;
    int kd = 0;
    for (; kd + 2 <= nd2; kd += 2) {  // 2-way unroll: 2 loads in flight
      int sk0 = tt * D_ + klist[kd];
      int sk1 = tt * D_ + klist[kd + 1];
      float p0 = q * qkvb[(size_t)sk0 * 384 + P_ + tid];
      float p1 = q * qkvb[(size_t)sk1 * 384 + P_ + tid];
#pragma unroll
      for (int m = 1; m < 32; m <<= 1) {
        p0 += __shfl_xor(p0, m);
        p1 += __shfl_xor(p1, m);
      }
      if (dd == 0) {
        scores[h][tp * nd2 + kd] = p0 * SCALE_;
        scores[h][tp * nd2 + kd + 1] = p1 * SCALE_;
      }
    }
    if (kd < nd2) {
      int sk = tt * D_ + klist[kd];
      float p = q * qkvb[(size_t)sk * 384 + P_ + tid];
#pragma unroll
      for (int m = 1; m < 32; m <<= 1) p += __shfl_xor(p, m);
      if (dd == 0) scores[h][tp * nd2 + kd] = p * SCALE_;
    }
  }
  // same-wave LDS visibility: head h's scores written by this wave
  float mx = -1e30f;
  for (int ki = dd; ki < nk; ki += 32) mx = fmaxf(mx, scores[h][ki]);
#pragma unroll
  for (int m = 1; m < 32; m <<= 1) mx = fmaxf(mx, __shfl_xor(mx, m));
  float ssum = 0.f;
  for (int ki = dd; ki < nk; ki += 32) {
    float e = expf(scores[h][ki] - mx);
    scores[h][ki] = e;
    ssum += e;
  }
#pragma unroll
  for (int m = 1; m < 32; m <<= 1) ssum += __shfl_xor(ssum, m);
  float inv = 1.f / ssum;

  float acc = 0.f;
  for (int tp = 0; tp < ntp; ++tp) {
    int tt = t0 + tp;
    int kd = 0;
    for (; kd + 2 <= nd2; kd += 2) {  // 2-way unroll
      float e0 = scores[h][tp * nd2 + kd];
      float e1 = scores[h][tp * nd2 + kd + 1];
      int sk0 = tt * D_ + klist[kd];
      int sk1 = tt * D_ + klist[kd + 1];
      float v0 = qkvb[(size_t)sk0 * 384 + 2 * P_ + tid];
      float v1 = qkvb[(size_t)sk1 * 384 + 2 * P_ + tid];
      acc = fmaf(e0, v0, acc);
      acc = fmaf(e1, v1, acc);
    }
    if (kd < nd2) {
      float e = scores[h][tp * nd2 + kd];
      int sk = tt * D_ + klist[kd];
      acc = fmaf(e, qkvb[(size_t)sk * 384 + 2 * P_ + tid], acc);
    }
  }
  att[tid] = acc * inv;
  __syncthreads();

  // Wo projection + residual
  int c = tid;
  float p = 0.f;
  for (int k = 0; k < 128; k += 4) {
    const float4 a = *(const float4*)&att[k];
    p = fmaf(a.x, Wo[(size_t)(k + 0) * P_ + c], p);
    p = fmaf(a.y, Wo[(size_t)(k + 1) * P_ + c], p);
    p = fmaf(a.z, Wo[(size_t)(k + 2) * P_ + c], p);
    p = fmaf(a.w, Wo[(size_t)(k + 3) * P_ + c], p);
  }
  z[(size_t)s * P_ + c] += p + bo[c];
}

// ---------------------------------------------------------------------------
// K3/K5: FFN (+ next-layer qkv OR head pre-projection). BM=4, NT=512,
// grid 768 (24 waves/CU). z round-trips eliminated: next stage consumes the
// new z straight from LDS. NEXT_QKV: write z + qkvb. else: write pre only.
// ---------------------------------------------------------------------------
template <bool NEXT_QKV>
__global__ __launch_bounds__(512) void ffn_next_kernel(
    const float* __restrict__ W1, const float* __restrict__ b1,
    const float* __restrict__ W2, const float* __restrict__ b2,
    const float* __restrict__ g2, const float* __restrict__ beta2,
    const float* __restrict__ Wqkv, const float* __restrict__ bqkv,
    const float* __restrict__ g1, const float* __restrict__ beta1,
    const float* __restrict__ Wc1, const float* __restrict__ Wd1,
    float* __restrict__ z, float* __restrict__ qkvb, float* __restrict__ pre) {
  constexpr int BM = 4;
  int m0 = blockIdx.x * BM;
  int tid = threadIdx.x;
  __shared__ float As[BM * 128];   // z-in, later LN1 output
  __shared__ float ys[BM * 128];   // LN2 output, later new z
  __shared__ float mid[BM * FF_];  // 8 KB
  if (tid < BM * 32)
    ((float4*)As)[tid] = ((const float4*)(z + (size_t)m0 * 128))[tid];
  __syncthreads();
  {  // LN2 -> ys (waves 0..3)
    int wv = tid >> 6, lane = tid & 63;
    if (wv < BM) {
      float v0 = As[wv * 128 + lane], v1 = As[wv * 128 + 64 + lane];
      float s = wave_sum64(v0 + v1);
      float mean = s * (1.f / 128.f);
      float d0 = v0 - mean, d1 = v1 - mean;
      float q = wave_sum64(d0 * d0 + d1 * d1);
      float inv = 1.f / sqrtf(q * (1.f / 128.f) + 1e-5f);
      ys[wv * 128 + lane] = d0 * inv * g2[lane] + beta2[lane];
      ys[wv * 128 + 64 + lane] = d1 * inv * g2[lane + 64] + beta2[lane + 64];
    }
  }
  __syncthreads();
  {  // FF1: col = tid (512), 4 rows
    int col = tid;
    float acc[BM];
    float bb = b1[col];
#pragma unroll
    for (int r = 0; r < BM; ++r) acc[r] = bb;
    for (int k = 0; k < 128; k += 4) {
      float w0 = W1[(size_t)(k + 0) * FF_ + col];
      float w1 = W1[(size_t)(k + 1) * FF_ + col];
      float w2 = W1[(size_t)(k + 2) * FF_ + col];
      float w3 = W1[(size_t)(k + 3) * FF_ + col];
#pragma unroll
      for (int r = 0; r < BM; ++r) {
        const float4 a = *(const float4*)&ys[r * 128 + k];
        acc[r] = fmaf(a.x, w0, acc[r]);
        acc[r] = fmaf(a.y, w1, acc[r]);
        acc[r] = fmaf(a.z, w2, acc[r]);
        acc[r] = fmaf(a.w, w3, acc[r]);
      }
    }
#pragma unroll
    for (int r = 0; r < BM; ++r) mid[r * FF_ + col] = fmaxf(acc[r], 0.f);
  }
  __syncthreads();
  {  // FF2 + residual -> new z in ys (4 rowgroups x 128 cols, 1 row each)
    int rg = tid >> 7, col = tid & 127;
    float a0 = 0.f;
    for (int k = 0; k < FF_; k += 4) {
      float w0 = W2[(size_t)(k + 0) * P_ + col];
      float w1 = W2[(size_t)(k + 1) * P_ + col];
      float w2 = W2[(size_t)(k + 2) * P_ + col];
      float w3 = W2[(size_t)(k + 3) * P_ + col];
      const float4 m0v = *(const float4*)&mid[rg * FF_ + k];
      a0 = fmaf(m0v.x, w0, a0); a0 = fmaf(m0v.y, w1, a0);
      a0 = fmaf(m0v.z, w2, a0); a0 = fmaf(m0v.w, w3, a0);
    }
    float nz = As[rg * 128 + col] + a0 + b2[col];
    __syncthreads();  // all FF2 reads of ys-era data & As residual done
    ys[rg * 128 + col] = nz;
    if (NEXT_QKV) z[(size_t)(m0 + rg) * P_ + col] = nz;
  }
  __syncthreads();
  if constexpr (NEXT_QKV) {
    {  // LN1 of new z -> As (waves 0..3)
      int wv = tid >> 6, lane = tid & 63;
      if (wv < BM) {
        float v0 = ys[wv * 128 + lane], v1 = ys[wv * 128 + 64 + lane];
        float s = wave_sum64(v0 + v1);
        float mean = s * (1.f / 128.f);
        float d0 = v0 - mean, d1 = v1 - mean;
        float q = wave_sum64(d0 * d0 + d1 * d1);
        float inv = 1.f / sqrtf(q * (1.f / 128.f) + 1e-5f);
        As[wv * 128 + lane] = d0 * inv * g1[lane] + beta1[lane];
        As[wv * 128 + 64 + lane] = d1 * inv * g1[lane + 64] + beta1[lane + 64];
      }
    }
    __syncthreads();
    if (tid < 384) {  // qkv: col = tid, 4 rows
      int col = tid;
      float acc[BM];
      float bc = bqkv[col];
#pragma unroll
      for (int r = 0; r < BM; ++r) acc[r] = bc;
      for (int k = 0; k < 128; k += 4) {
        float b0 = Wqkv[(size_t)(k + 0) * 384 + col];
        float b1 = Wqkv[(size_t)(k + 1) * 384 + col];
        float b2c = Wqkv[(size_t)(k + 2) * 384 + col];
        float b3 = Wqkv[(size_t)(k + 3) * 384 + col];
#pragma unroll
        for (int r = 0; r < BM; ++r) {
          const float4 a = *(const float4*)&As[r * 128 + k];
          acc[r] = fmaf(a.x, b0, acc[r]);
          acc[r] = fmaf(a.y, b1, acc[r]);
          acc[r] = fmaf(a.z, b2c, acc[r]);
          acc[r] = fmaf(a.w, b3, acc[r]);
        }
      }
#pragma unroll
      for (int r = 0; r < BM; ++r) qkvb[(size_t)(m0 + r) * 384 + col] = acc[r];
    }
  } else {
    // pre = newz @ [Wc1[:P] | Wc1[P:2P] | Wd1[:P] | Wd1[P:]] from ys
    int col = tid;
    int seg = col >> 7, cc = col & 127;
    const float* Bbase = (seg < 2 ? Wc1 : Wd1) + ((seg & 1) ? P_ * P_ : 0) + cc;
    float acc[BM];
#pragma unroll
    for (int r = 0; r < BM; ++r) acc[r] = 0.f;
    for (int k = 0; k < 128; k += 4) {
      float b0 = Bbase[(size_t)(k + 0) * P_];
      float b1 = Bbase[(size_t)(k + 1) * P_];
      float b2c = Bbase[(size_t)(k + 2) * P_];
      float b3 = Bbase[(size_t)(k + 3) * P_];
#pragma unroll
      for (int r = 0; r < BM; ++r) {
        const float4 a = *(const float4*)&ys[r * 128 + k];
        acc[r] = fmaf(a.x, b0, acc[r]);
        acc[r] = fmaf(a.y, b1, acc[r]);
        acc[r] = fmaf(a.z, b2c, acc[r]);
        acc[r] = fmaf(a.w, b3, acc[r]);
      }
    }
#pragma unroll
    for (int r = 0; r < BM; ++r) pre[(size_t)(m0 + r) * 512 + col] = acc[r];
  }
}

// ---------------------------------------------------------------------------
// Logits (active entries; full -1e9 fill) + dist epilogue. grid (D_, T_-1).
// ---------------------------------------------------------------------------
__global__ __launch_bounds__(64) void logits_dist_kernel(
    const float* __restrict__ pre, const int* __restrict__ adj_cnt,
    const int* __restrict__ adj_list, const float* __restrict__ edge_w,
    const float* __restrict__ W_edge, const float* __restrict__ b_edge,
    const float* __restrict__ Wc1e, const float* __restrict__ bc1,
    const float* __restrict__ Wc2, const float* __restrict__ bc2,
    const float* __restrict__ bd1, const float* __restrict__ Wd2,
    const float* __restrict__ bd2, float* __restrict__ logits,
    float* __restrict__ dist) {
  int i = blockIdx.x;
  int t = blockIdx.y;
  int lane = threadIdx.x;
  int w = t * D_ + i;
  float* lrow = logits + (size_t)w * D_;
  for (int j = lane; j < D_; j += 64) lrow[j] = -1e9f;

  const float* hnr = pre + (size_t)((t + 1) * D_ + i) * 512;
  float hn0 = hnr[lane], hn1 = hnr[lane + 64];
  float bc1_0 = bc1[lane], bc1_1 = bc1[lane + 64];
  float wc0 = Wc2[lane], wc1 = Wc2[lane + 64];
  float bb = bc2[0];
  int cnt = adj_cnt[i];
  for (int jj = 0; jj < cnt; ++jj) {
    int j = adj_list[i * D_ + jj];
    float wv = edge_w[i * D_ + j];
    float he0 = 0.f, he1 = 0.f;
#pragma unroll 8
    for (int e = 0; e < EC_; ++e) {
      float enc = fmaxf(fmaf(wv, W_edge[e], b_edge[e]), 0.f);
      he0 = fmaf(enc, Wc1e[e * P_ + lane], he0);
      he1 = fmaf(enc, Wc1e[e * P_ + lane + 64], he1);
    }
    const float* hcr = pre + (size_t)(t * D_ + j) * 512 + 128;
    float sacc = fmaxf(hn0 + hcr[lane] + he0 + bc1_0, 0.f) * wc0 +
                 fmaxf(hn1 + hcr[lane + 64] + he1 + bc1_1, 0.f) * wc1;
    sacc = wave_sum64(sacc);
    if (lane == 0) lrow[j] = sacc + bb;
  }

  const float* ar = pre + (size_t)w * 512 + 256;
  const float* br = pre + (size_t)(w + D_) * 512 + 384;
  float v0 = fmaxf(ar[lane] + br[lane] + bd1[lane], 0.f) * Wd2[lane];
  float v1 = fmaxf(ar[lane + 64] + br[lane + 64] + bd1[lane + 64], 0.f) * Wd2[lane + 64];
  float sd = wave_sum64(v0 + v1);
  if (lane == 0) dist[w] = sd + bd2[0];
}

// ---------------------------------------------------------------------------
extern "C" void kernel_launch(void* const* d_in, const int* in_sizes, int n_in,
                              void* d_out, int out_size, void* d_ws,
                              size_t ws_size, hipStream_t stream) {
  const float* x = (const float*)d_in[0];
  const float* edge_w = (const float*)d_in[1];
  const float* W_node = (const float*)d_in[2];
  const float* b_node = (const float*)d_in[3];
  const float* W_edge = (const float*)d_in[4];
  const float* b_edge = (const float*)d_in[5];
  const float* time_enc = (const float*)d_in[6];
  const float* Wqkv = (const float*)d_in[7];
  const float* bqkv = (const float*)d_in[8];
  const float* Wo = (const float*)d_in[9];
  const float* bo = (const float*)d_in[10];
  const float* W1 = (const float*)d_in[11];
  const float* b1 = (const float*)d_in[12];
  const float* W2 = (const float*)d_in[13];
  const float* b2 = (const float*)d_in[14];
  const float* g1 = (const float*)d_in[15];
  const float* beta1 = (const float*)d_in[16];
  const float* g2 = (const float*)d_in[17];
  const float* beta2 = (const float*)d_in[18];
  const float* Wc1 = (const float*)d_in[19];
  const float* bc1 = (const float*)d_in[20];
  const float* Wc2 = (const float*)d_in[21];
  const float* bc2 = (const float*)d_in[22];
  const float* Wd1 = (const float*)d_in[23];
  const float* bd1 = (const float*)d_in[24];
  const float* Wd2 = (const float*)d_in[25];
  const float* bd2 = (const float*)d_in[26];

  float* ws = (float*)d_ws;
  float* z = ws;                   // S*128
  float* qkvb = z + S_ * 128;      // S*384
  float* pre = qkvb + S_ * 384;    // S*512
  int* adj_cnt = (int*)(pre + S_ * 512);  // D_
  int* adj_list = adj_cnt + D_;           // D_*D_

  float* logits = (float*)d_out;
  float* dist = (float*)d_out + (T_ - 1) * D_ * D_;

  // K1: embed + LN1 + qkv (layer 1)
  embed_qkv_kernel<<<S_ / 6, 384, 0, stream>>>(
      x, W_node, b_node, time_enc, edge_w, Wqkv, bqkv, g1, beta1, z, qkvb,
      adj_cnt, adj_list);
  // K2: attention layer 1
  attn_wo_kernel<<<S_, 128, 0, stream>>>(qkvb, adj_cnt, adj_list, Wo, bo, z);
  // K3: FFN layer 1 + LN1 + qkv (layer 2)
  ffn_next_kernel<true><<<S_ / 4, 512, 0, stream>>>(
      W1, b1, W2, b2, g2, beta2, Wqkv, bqkv, g1, beta1, nullptr, nullptr, z,
      qkvb, nullptr);
  // K4: attention layer 2
  attn_wo_kernel<<<S_, 128, 0, stream>>>(qkvb, adj_cnt, adj_list, Wo, bo, z);
  // K5: FFN layer 2 + head pre-projection (z never written back)
  ffn_next_kernel<false><<<S_ / 4, 512, 0, stream>>>(
      W1, b1, W2, b2, g2, beta2, nullptr, nullptr, nullptr, nullptr, Wc1, Wd1,
      z, nullptr, pre);
  // K6: logits + dist
  logits_dist_kernel<<<dim3(D_, T_ - 1), 64, 0, stream>>>(
      pre, adj_cnt, adj_list, edge_w, W_edge, b_edge, Wc1 + 2 * P_ * P_, bc1,
      Wc2, bc2, bd1, Wd2, bd2, logits, dist);
}